// Round 5
// baseline (19739.781 us; speedup 1.0000x reference)
//
#include <hip/hip_runtime.h>
#include <cstddef>

// Problem constants (fixed by the reference).
#define BATCH   4096
#define NBLK    100
#define NSLOT   300
#define NSTATE  1436
#define HID     256
#define NSTEPS  100
#define NEGV    (-1000.0f)
#define KC      384      // OpenBLAS sgemm K-panel (SGEMM_DEFAULT_Q)

// Bit-faithful *float32* path (verified absmax=0.0 in round 4):
//  - per-element ascending-k fmaf chain, KC=384 panel commits for K>384
//  - separately-rounded bias adds; np op order everywhere
//  - gates: ((x@Wih.T + bih) + h@Whh.T) + bhh
//  - f32 exp/tanh via f64 libm rounded to f32 (matches numpy)
// Optimizations must preserve these per-element chains exactly; only the
// element->thread partitioning may change.

__device__ __forceinline__ float sigf(float x) {
#pragma clang fp contract(off)
  float e = (float)exp(-(double)x);
  float d = 1.0f + e;
  return 1.0f / d;
}
__device__ __forceinline__ float tanhf32(float x) {
  return (float)tanh((double)x);
}

// first-max argmax across a wave64; result broadcast to all lanes.
__device__ __forceinline__ void argmax64f(float& v, int& i) {
#pragma unroll
  for (int off = 32; off > 0; off >>= 1) {
    float v2 = __shfl_down(v, off, 64);
    int   i2 = __shfl_down(i, off, 64);
    if (v2 > v || (v2 == v && i2 < i)) { v = v2; i = i2; }
  }
  v = __shfl(v, 0, 64);
  i = __shfl(i, 0, 64);
}

// ---------------------------------------------------------------------------
// state concat (also the A-source for the first MLP GEMM)
// ---------------------------------------------------------------------------
__global__ __launch_bounds__(256) void concat_kernel(
    const float* __restrict__ to_t, const float* __restrict__ ti_t,
    const float* __restrict__ ys_t, float* __restrict__ state)
{
  int b = blockIdx.x;
  for (int li = threadIdx.x; li < 7180; li += 256) {
    float v = (li < 500)  ? to_t[(size_t)b * 500 + li]
            : (li < 1000) ? ti_t[(size_t)b * 500 + (li - 500)]
                          : ys_t[(size_t)b * 6180 + (li - 1000)];
    state[(size_t)b * 7180 + li] = v;
  }
}

// ---------------------------------------------------------------------------
// Generic f32 GEMM tile: C[64x64] = act(A @ W^T + bias)  (features + logits)
// ---------------------------------------------------------------------------
__device__ __forceinline__ void gemm32_tile(
    const float* __restrict__ A, int lda,
    const float* __restrict__ W, int ldw,
    const float* __restrict__ bias,
    float* __restrict__ C, int ldc,
    int N, int K, int row0, int col0, bool relu)
{
#pragma clang fp contract(off)
  __shared__ float As[16][68];
  __shared__ float Ws[16][68];
  const int t = threadIdx.x;
  const int tx = t & 15, ty = t >> 4;
  const int mload = t >> 2;          // 0..63
  const int kq    = (t & 3) << 2;    // 0,4,8,12
  const int gn    = col0 + mload;
  const float* Aptr = A + (size_t)(row0 + mload) * lda + kq;
  const float* Wptr = (gn < N) ? (W + (size_t)gn * ldw + kq) : nullptr;

  float acc[4][4] = {};
  float res[4][4];
  bool first = true;
  for (int k0 = 0; k0 < K; k0 += 16) {
    if (k0 > 0 && (k0 % KC) == 0) {  // sgemm K-panel boundary: commit panel
#pragma unroll
      for (int i = 0; i < 4; i++)
#pragma unroll
        for (int j = 0; j < 4; j++) {
          res[i][j] = first ? acc[i][j] : (res[i][j] + acc[i][j]);
          acc[i][j] = 0.0f;
        }
      first = false;
    }
    float4 av = *(const float4*)(Aptr + k0);
    float4 wv = make_float4(0.f, 0.f, 0.f, 0.f);
    if (Wptr) wv = *(const float4*)(Wptr + k0);
    As[kq + 0][mload] = av.x; As[kq + 1][mload] = av.y;
    As[kq + 2][mload] = av.z; As[kq + 3][mload] = av.w;
    Ws[kq + 0][mload] = wv.x; Ws[kq + 1][mload] = wv.y;
    Ws[kq + 2][mload] = wv.z; Ws[kq + 3][mload] = wv.w;
    __syncthreads();
#pragma unroll
    for (int kk = 0; kk < 16; kk++) {
      float a[4], w[4];
#pragma unroll
      for (int i = 0; i < 4; i++) { a[i] = As[kk][ty * 4 + i]; w[i] = Ws[kk][tx * 4 + i]; }
#pragma unroll
      for (int i = 0; i < 4; i++)
#pragma unroll
        for (int j = 0; j < 4; j++) acc[i][j] = fmaf(a[i], w[j], acc[i][j]);
    }
    __syncthreads();
  }
#pragma unroll
  for (int i = 0; i < 4; i++)
#pragma unroll
    for (int j = 0; j < 4; j++)
      res[i][j] = first ? acc[i][j] : (res[i][j] + acc[i][j]);

#pragma unroll
  for (int i = 0; i < 4; i++) {
    size_t row = (size_t)(row0 + ty * 4 + i) * ldc;
#pragma unroll
    for (int j = 0; j < 4; j++) {
      int n = col0 + tx * 4 + j;
      if (n < N) {
        float v = res[i][j] + bias[n];
        if (relu) v = v > 0.0f ? v : 0.0f;
        C[row + n] = v;
      }
    }
  }
}

__global__ __launch_bounds__(256) void gemm32_kernel(
    const float* __restrict__ A, int lda, const float* __restrict__ W, int ldw,
    const float* __restrict__ bias, float* __restrict__ C, int ldc,
    int N, int K, int relu)
{
  gemm32_tile(A, lda, W, ldw, bias, C, ldc, N, K,
              blockIdx.y * 64, blockIdx.x * 64, relu != 0);
}

// ---------------------------------------------------------------------------
// GEMM1: X1[r, o] = relu( sum_n state[b, n, j] * W1[o, n] + b1[o] )
// R = row_base + r, b = R/5, j = R%5. K=1436 -> panels 384/384/384/284.
// ---------------------------------------------------------------------------
__global__ __launch_bounds__(256) void gemm1_kernel(
    const float* __restrict__ state, const float* __restrict__ W1,
    const float* __restrict__ b1, float* __restrict__ X1, int row_base)
{
#pragma clang fp contract(off)
  __shared__ float As[16][68];
  __shared__ float Ws[16][68];
  const int t = threadIdx.x;
  const int tx = t & 15, ty = t >> 4;
  const int mload = t >> 2;
  const int kq    = (t & 3) << 2;
  const int row0 = blockIdx.y * 64, col0 = blockIdx.x * 64;
  const int R = row_base + row0 + mload;
  const int b = R / 5, j = R - b * 5;
  const float* sp = state + (size_t)b * 7180 + j;
  const float* Wptr = W1 + (size_t)(col0 + mload) * NSTATE + kq;

  float acc[4][4] = {};
  float res[4][4];
  bool first = true;
  for (int k0 = 0; k0 < 1440; k0 += 16) {
    if (k0 == 384 || k0 == 768 || k0 == 1152) {
#pragma unroll
      for (int i = 0; i < 4; i++)
#pragma unroll
        for (int jj = 0; jj < 4; jj++) {
          res[i][jj] = first ? acc[i][jj] : (res[i][jj] + acc[i][jj]);
          acc[i][jj] = 0.0f;
        }
      first = false;
    }
    int n = k0 + kq;
    float a0 = (n + 0 < NSTATE) ? sp[(n + 0) * 5] : 0.0f;
    float a1 = (n + 1 < NSTATE) ? sp[(n + 1) * 5] : 0.0f;
    float a2 = (n + 2 < NSTATE) ? sp[(n + 2) * 5] : 0.0f;
    float a3 = (n + 3 < NSTATE) ? sp[(n + 3) * 5] : 0.0f;
    float4 wv = make_float4(0.f, 0.f, 0.f, 0.f);
    if (n + 3 < NSTATE) wv = *(const float4*)(Wptr + k0);
    As[kq + 0][mload] = a0; As[kq + 1][mload] = a1;
    As[kq + 2][mload] = a2; As[kq + 3][mload] = a3;
    Ws[kq + 0][mload] = wv.x; Ws[kq + 1][mload] = wv.y;
    Ws[kq + 2][mload] = wv.z; Ws[kq + 3][mload] = wv.w;
    __syncthreads();
#pragma unroll
    for (int kk = 0; kk < 16; kk++) {
      float a[4], w[4];
#pragma unroll
      for (int i = 0; i < 4; i++) { a[i] = As[kk][ty * 4 + i]; w[i] = Ws[kk][tx * 4 + i]; }
#pragma unroll
      for (int i = 0; i < 4; i++)
#pragma unroll
        for (int jj = 0; jj < 4; jj++) acc[i][jj] = fmaf(a[i], w[jj], acc[i][jj]);
    }
    __syncthreads();
  }
#pragma unroll
  for (int i = 0; i < 4; i++)
#pragma unroll
    for (int jj = 0; jj < 4; jj++)
      res[i][jj] = res[i][jj] + acc[i][jj];   // last (4th) panel commit

#pragma unroll
  for (int i = 0; i < 4; i++) {
    size_t row = (size_t)(row0 + ty * 4 + i) * 512;
#pragma unroll
    for (int jj = 0; jj < 4; jj++) {
      int n = col0 + tx * 4 + jj;
      float v = res[i][jj] + b1[n];
      X1[row + n] = v > 0.0f ? v : 0.0f;
    }
  }
}

// ---------------------------------------------------------------------------
// feat2: feat_vec[b,k] = sum_j X3[(bl*5+j),k]*W_fe2[j] + b_fe2 ; init h/c.
// ---------------------------------------------------------------------------
__global__ __launch_bounds__(256) void feat2c_kernel(
    const float* __restrict__ X3, const float* __restrict__ W_fe2,
    const float* __restrict__ b_fe2, float* __restrict__ hto,
    float* __restrict__ cto, float* __restrict__ hti, float* __restrict__ cti,
    int b_base)
{
#pragma clang fp contract(off)
  int bl = blockIdx.x, b = b_base + bl, k = threadIdx.x;
  float s = 0.0f;
#pragma unroll
  for (int j = 0; j < 5; j++)
    s = fmaf(X3[((size_t)bl * 5 + j) * 256 + k], W_fe2[j], s);
  float acc = s + b_fe2[0];
  hto[(size_t)b * 256 + k] = acc;
  hti[(size_t)b * 256 + k] = acc;
  cto[(size_t)b * 256 + k] = 0.0f;
  cti[(size_t)b * 256 + k] = 0.0f;
}

// ---------------------------------------------------------------------------
// init: mutable slots copy + masks + zero inp_buf
// ---------------------------------------------------------------------------
__global__ __launch_bounds__(320) void init_state_kernel(
    const float* __restrict__ to_t, const float* __restrict__ ti_t,
    const float* __restrict__ slot_info, float* __restrict__ slots,
    int* __restrict__ m_to, int* __restrict__ m_ti, float* __restrict__ inp)
{
  int b = blockIdx.x, t = threadIdx.x;
  for (int li = t; li < NSLOT * 5; li += 320)
    slots[(size_t)b * (NSLOT * 5) + li] = slot_info[(size_t)b * (NSLOT * 5) + li];
  if (t < NBLK) {
    m_to[b * 128 + t] = (to_t[(size_t)b * 500 + t * 5] != -1.0f) ? 1 : 0;
    m_ti[b * 128 + t] = (ti_t[(size_t)b * 500 + t * 5] != -1.0f) ? 1 : 0;
  }
  if (t < 8) inp[b * 8 + t] = 0.0f;
}

// init: concatenated logits weights [Wb;Ws] (exact copies)
__global__ __launch_bounds__(256) void init_weights_kernel(
    const float* __restrict__ Wb, const float* __restrict__ bb,
    const float* __restrict__ Ws, const float* __restrict__ bs,
    float* __restrict__ Wcat, float* __restrict__ bcat)
{
  int idx = blockIdx.x * 256 + threadIdx.x;
  if (idx < 400 * 256) {
    int n = idx / 256, k = idx % 256;
    Wcat[idx] = (n < 100) ? Wb[n * 256 + k] : Ws[(n - 100) * 256 + k];
  }
  if (idx < 400) bcat[idx] = (idx < 100) ? bb[idx] : bs[idx - 100];
}

// ---------------------------------------------------------------------------
// FUSED gates + LSTM, both cells (blockIdx.z: 0=to, 1=ti).
// Block computes a 64-row x 64-u tile of ALL FOUR gate quadrants
// (o = q*256+u), then does the LSTM pointwise in-register and writes h/c.
// Per-element rounding identical to round-4 (single ascending fmaf chain
// K=256; ((ih+bih)+hh)+bhh; np pointwise order; double-libm transcendentals).
// h is ping-pong (h_in -> h_out) since other blocks read full h rows.
// ---------------------------------------------------------------------------
__global__ __launch_bounds__(256, 2) void gates_lstm_kernel(
    const float* __restrict__ hin_to, const float* __restrict__ hin_ti,
    float* __restrict__ hout_to, float* __restrict__ hout_ti,
    float* __restrict__ cto, float* __restrict__ cti,
    const float* __restrict__ Whh_to, const float* __restrict__ Wih_to,
    const float* __restrict__ bih_to, const float* __restrict__ bhh_to,
    const float* __restrict__ Whh_ti,
    const float* __restrict__ bih_ti, const float* __restrict__ bhh_ti,
    const float* __restrict__ inp)
{
#pragma clang fp contract(off)
  __shared__ float As[32][68];
  __shared__ float Wsh[32][272];
  const bool is_to = (blockIdx.z == 0);
  const float* __restrict__ h_in  = is_to ? hin_to : hin_ti;
  float* __restrict__ h_out = is_to ? hout_to : hout_ti;
  float* __restrict__ cbuf  = is_to ? cto : cti;
  const float* __restrict__ Whh = is_to ? Whh_to : Whh_ti;
  const float* __restrict__ bih = is_to ? bih_to : bih_ti;
  const float* __restrict__ bhh = is_to ? bhh_to : bhh_ti;

  const int t  = threadIdx.x;
  const int tx = t & 15, ty = t >> 4;
  const int u0   = blockIdx.x * 64;
  const int row0 = blockIdx.y * 64;
  const int rr   = t >> 3;            // 0..31
  const int kq8  = (t & 7) << 2;      // 0,4,...,28

  float acc[4][4][4] = {};            // [q][i][j]

  for (int k0 = 0; k0 < 256; k0 += 32) {
    // stage A: 64 rows x 32 k  (2 passes of 32 rows)
#pragma unroll
    for (int p = 0; p < 2; p++) {
      int r = p * 32 + rr;
      float4 v = *(const float4*)(h_in + (size_t)(row0 + r) * 256 + k0 + kq8);
      As[kq8 + 0][r] = v.x; As[kq8 + 1][r] = v.y;
      As[kq8 + 2][r] = v.z; As[kq8 + 3][r] = v.w;
    }
    // stage W: 256 gate-rows (4 quadrants x 64 u) x 32 k  (8 passes)
#pragma unroll
    for (int p = 0; p < 8; p++) {
      int r = p * 32 + rr;            // 0..255
      int q = r >> 6, c = r & 63;
      float4 v = *(const float4*)(Whh + (size_t)(q * 256 + u0 + c) * 256 + k0 + kq8);
      Wsh[kq8 + 0][q * 68 + c] = v.x; Wsh[kq8 + 1][q * 68 + c] = v.y;
      Wsh[kq8 + 2][q * 68 + c] = v.z; Wsh[kq8 + 3][q * 68 + c] = v.w;
    }
    __syncthreads();
#pragma unroll
    for (int kk = 0; kk < 32; kk++) {
      float4 a4 = *(const float4*)&As[kk][ty * 4];
      float a[4] = {a4.x, a4.y, a4.z, a4.w};
#pragma unroll
      for (int q = 0; q < 4; q++) {
        float4 w4 = *(const float4*)&Wsh[kk][q * 68 + tx * 4];
        float w[4] = {w4.x, w4.y, w4.z, w4.w};
#pragma unroll
        for (int i = 0; i < 4; i++)
#pragma unroll
          for (int j = 0; j < 4; j++)
            acc[q][i][j] = fmaf(a[i], w[j], acc[q][i][j]);
      }
    }
    __syncthreads();
  }

  // ---- epilogue: gates assembly + LSTM pointwise (np rounding order) ----
  float xv[4][5];
#pragma unroll
  for (int i = 0; i < 4; i++) {
    int r = row0 + ty * 4 + i;
#pragma unroll
    for (int k5 = 0; k5 < 5; k5++)
      xv[i][k5] = is_to ? inp[r * 8 + k5] : 0.0f;
  }
#pragma unroll
  for (int j = 0; j < 4; j++) {
    int u = u0 + tx * 4 + j;
    float gv[4][4];                   // [q][i]
#pragma unroll
    for (int q = 0; q < 4; q++) {
      int o = q * 256 + u;
      float bihv = bih[o], bhhv = bhh[o];
      float wih[5];
#pragma unroll
      for (int k5 = 0; k5 < 5; k5++) wih[k5] = is_to ? Wih_to[o * 5 + k5] : 0.0f;
#pragma unroll
      for (int i = 0; i < 4; i++) {
        float ih = 0.0f;
#pragma unroll
        for (int k5 = 0; k5 < 5; k5++) ih = fmaf(xv[i][k5], wih[k5], ih);
        float v1 = ih + bihv;         // x@Wih.T + bih   (rounded)
        float v2 = v1 + acc[q][i][j]; // ... + h@Whh.T   (rounded)
        float v3 = v2 + bhhv;         // ... + bhh       (rounded)
        gv[q][i] = v3;
      }
    }
#pragma unroll
    for (int i = 0; i < 4; i++) {
      int r = row0 + ty * 4 + i;
      float i_ = gv[0][i], f_ = gv[1][i], gg = gv[2][i], o_ = gv[3][i];
      float sf = sigf(f_);
      float si = sigf(i_);
      float tg = tanhf32(gg);
      float cp = cbuf[(size_t)r * 256 + u];
      float t2 = sf * cp;
      float t5 = si * tg;
      float cc = t2 + t5;
      cbuf[(size_t)r * 256 + u] = cc;
      float so = sigf(o_);
      float tc = tanhf32(cc);
      h_out[(size_t)r * 256 + u] = so * tc;
    }
  }
}

// logits. L[b,0:400] = h_to @ [Wb;Ws]^T + [bb;bs] ; L[b,400:500] = h_ti @ Wb^T + bb
__global__ __launch_bounds__(256) void logits32_kernel(
    const float* __restrict__ hto, const float* __restrict__ hti,
    const float* __restrict__ Wcat, const float* __restrict__ bcat,
    const float* __restrict__ Wb, const float* __restrict__ bb,
    float* __restrict__ L)
{
  int ct = blockIdx.x;              // 0..8
  if (ct < 7)
    gemm32_tile(hto, 256, Wcat, 256, bcat, L, 512, 400, 256,
                blockIdx.y * 64, ct * 64, false);
  else
    gemm32_tile(hti, 256, Wb, 256, bb, L + 400, 512, 100, 256,
                blockIdx.y * 64, (ct - 7) * 64, false);
}

// per-batch selection + state updates (one wave64 per batch row)
__global__ __launch_bounds__(64) void select32_kernel(
    const float* __restrict__ L, const float* __restrict__ to_t,
    int* __restrict__ m_to, int* __restrict__ m_ti, float* __restrict__ slots,
    float* __restrict__ inp, float* __restrict__ out_act, int step)
{
  int b = blockIdx.x, lane = threadIdx.x;
  const float* Lr = L + (size_t)b * 512;

  float bv = -3.4e38f; int bi = 0x7fffffff;
  for (int n = lane; n < NBLK; n += 64) {
    float v = m_to[b * 128 + n] ? Lr[n] : NEGV;
    if (v > bv) { bv = v; bi = n; }
  }
  argmax64f(bv, bi);
  int sel_b = bi;
  const float* blk = to_t + (size_t)b * 500 + sel_b * 5;
  float i0 = blk[0], i1 = blk[1];
  if (lane == 0) m_to[b * 128 + sel_b] = 0;
  if (lane < 5) inp[b * 8 + lane] = blk[lane];

  float sv = -3.4e38f; int si = 0x7fffffff;
  float* sl = slots + (size_t)b * (NSLOT * 5);
  for (int s = lane; s < NSLOT; s += 64) {
    float l = sl[s * 5 + 0], w = sl[s * 5 + 1];
    bool mask = (i0 >= l) || (i1 >= w) || (l == 0.0f);
    float v = mask ? NEGV : Lr[100 + s];
    if (v > sv) { sv = v; si = s; }
  }
  argmax64f(sv, si);
  int sel_s = si;
  if (lane == 0) {
    float c = sl[sel_s * 5 + 4] - 1.0f;
    if (c == 0.0f) {
      sl[sel_s * 5 + 0] = 0.f; sl[sel_s * 5 + 1] = 0.f; sl[sel_s * 5 + 2] = 0.f;
      sl[sel_s * 5 + 3] = 0.f; sl[sel_s * 5 + 4] = 0.f;
    } else {
      sl[sel_s * 5 + 4] = c;
    }
  }

  float tv = -3.4e38f; int tii = 0x7fffffff;
  for (int n = lane; n < NBLK; n += 64) {
    float v = m_ti[b * 128 + n] ? Lr[400 + n] : NEGV;
    if (v > tv) { tv = v; tii = n; }
  }
  argmax64f(tv, tii);
  if (lane == 0) {
    m_ti[b * 128 + tii] = 0;
    float* oa = out_act + (size_t)b * (NSTEPS * 3) + step * 3;
    oa[0] = (float)sel_b; oa[1] = (float)sel_s; oa[2] = (float)tii;
  }
}

// ---------------------------------------------------------------------------
extern "C" void kernel_launch(void* const* d_in, const int* in_sizes, int n_in,
                              void* d_out, int out_size, void* d_ws, size_t ws_size,
                              hipStream_t stream) {
  (void)in_sizes; (void)n_in; (void)out_size; (void)ws_size;
  const float* to_t   = (const float*)d_in[0];
  const float* ti_t   = (const float*)d_in[1];
  const float* ys_t   = (const float*)d_in[2];
  const float* slot_i = (const float*)d_in[3];
  const float* W1 = (const float*)d_in[4];  const float* b1 = (const float*)d_in[5];
  const float* W2 = (const float*)d_in[6];  const float* b2 = (const float*)d_in[7];
  const float* W3 = (const float*)d_in[8];  const float* b3 = (const float*)d_in[9];
  const float* W_fe2 = (const float*)d_in[10]; const float* b_fe2 = (const float*)d_in[11];
  const float* Wih_to = (const float*)d_in[12]; const float* Whh_to = (const float*)d_in[13];
  const float* bih_to = (const float*)d_in[14]; const float* bhh_to = (const float*)d_in[15];
  const float* Whh_ti = (const float*)d_in[17];
  const float* bih_ti = (const float*)d_in[18]; const float* bhh_ti = (const float*)d_in[19];
  const float* Wb = (const float*)d_in[20]; const float* bb = (const float*)d_in[21];
  const float* Ws = (const float*)d_in[22]; const float* bs = (const float*)d_in[23];
  // Wih_ti (d_in[16]) unused: ti input is zeros -> ih == +0.0 exactly.

  float* outf      = (float*)d_out;
  float* state_out = outf;                               // 4096*1436*5 f32
  float* out_act   = outf + (size_t)BATCH * NSTATE * 5;  // 4096*100*3  f32

  // Workspace layout in floats (total ~76 MB).
  float* ws = (float*)d_ws;
  float* Lb    = ws;                       // 4096*512  = 2,097,152
  float* hA_to = ws + 2097152;             // 4096*256 = 1,048,576
  float* hA_ti = ws + 3145728;
  float* hB_to = ws + 4194304;
  float* hB_ti = ws + 5242880;
  float* cto   = ws + 6291456;
  float* cti   = ws + 7340032;
  float* slots = ws + 8388608;             // 4096*1500 = 6,144,000
  int*   m_to  = (int*)(ws + 14532608);    // 4096*128 = 524,288
  int*   m_ti  = (int*)(ws + 15056896);
  float* inp_buf = ws + 15581184;          // 4096*8 = 32,768
  float* Wcat  = ws + 15613952;            // 400*256 = 102,400
  float* bcat  = ws + 15716352;            // 400
  float* X1    = ws + 15720448;            // 2560*512 = 1,310,720
  float* X2    = ws + 17031168;            // 1,310,720
  float* X3    = ws + 18341888;            //   655,360  -> end 18,997,248

  concat_kernel<<<dim3(BATCH), 256, 0, stream>>>(to_t, ti_t, ys_t, state_out);
  init_state_kernel<<<dim3(BATCH), 320, 0, stream>>>(to_t, ti_t, slot_i, slots,
                                                     m_to, m_ti, inp_buf);
  init_weights_kernel<<<dim3(400), 256, 0, stream>>>(Wb, bb, Ws, bs, Wcat, bcat);

  // Feature MLP in 8 row-chunks of 2560 (512 batches each), f32 sgemm order.
  for (int c = 0; c < 8; c++) {
    int rb = c * 2560, b0 = c * 512;
    gemm1_kernel<<<dim3(8, 40), 256, 0, stream>>>(state_out, W1, b1, X1, rb);
    gemm32_kernel<<<dim3(8, 40), 256, 0, stream>>>(X1, 512, W2, 512, b2,
                                                   X2, 512, 512, 512, 1);
    gemm32_kernel<<<dim3(4, 40), 256, 0, stream>>>(X2, 512, W3, 512, b3,
                                                   X3, 256, 256, 512, 1);
    feat2c_kernel<<<dim3(512), 256, 0, stream>>>(X3, W_fe2, b_fe2,
                                                 hA_to, cto, hA_ti, cti, b0);
  }

  // Sequential decode loop: 3 kernels/step, h ping-pong A<->B.
  for (int s = 0; s < NSTEPS; s++) {
    const float* hin_to = (s & 1) ? hB_to : hA_to;
    const float* hin_ti = (s & 1) ? hB_ti : hA_ti;
    float* hout_to = (s & 1) ? hA_to : hB_to;
    float* hout_ti = (s & 1) ? hA_ti : hB_ti;
    gates_lstm_kernel<<<dim3(4, 64, 2), 256, 0, stream>>>(
        hin_to, hin_ti, hout_to, hout_ti, cto, cti,
        Whh_to, Wih_to, bih_to, bhh_to, Whh_ti, bih_ti, bhh_ti, inp_buf);
    logits32_kernel<<<dim3(9, 64), 256, 0, stream>>>(hout_to, hout_ti,
                                                     Wcat, bcat, Wb, bb, Lb);
    select32_kernel<<<dim3(BATCH), 64, 0, stream>>>(Lb, to_t, m_to, m_ti, slots,
                                                    inp_buf, out_act, s);
  }
}